// Round 7
// baseline (135.992 us; speedup 1.0000x reference)
//
#include <hip/hip_runtime.h>

// N=524288, D=9, E=2, H=128, M=32, O=2, K=1.
// LAYOUT (confirmed R6): d_in fp32, d_out FP32 (N*2 outputs + 1 loss).
// NUMERICS: pure fp32; per-token fmaf chains identical to accepted kernel.
//
// R7 = R6 with the boundary-wave bias-indexing bug fixed:
//   was bpp[(eb>>10)|o] (expert1 -> bpp[1],bpp[1]); now bpp[ex*2+o].
// R6 architecture kept: weight delivery via REGISTERS + v_readlane.
// Model (fits R0-R5): wave-shared 48B/j weight delivery was the bottleneck
// in every prior form: SMEM s_load can't pipeline (drain waits, R0-R4,
// 43-62us); LDS broadcast replicates 64x on the 128B/cyc return bus ->
// 3x DS-oversubscribed (R5 predicted 36, measured ~38.5). Registers do
// neither: each expert pack (1536 f) lives distributed across a wave's
// lanes (24 VGPR/lane); per j, 12 v_readlane (VALU pipe, zero latency
// waits) broadcast the record. 4 tok/thread -> 15 VALU instr per token*j
// vs 12 floor => VALU-bound ~12.8us issue.
// Boundary wave (<=1/4): per-TOKEN per-lane ds_read_b128 (full return-bus
// utilization, handles the straddling thread naturally; no dense-both).
#define NTOK 524288
#define TPB  256
#define TOKB 1024             // tokens per block (4 per thread)
#define NBLK (NTOK / TOKB)    // 512

__device__ __forceinline__ float bf2f(unsigned short u) {
    union { unsigned int i; float f; } v;
    v.i = ((unsigned int)u) << 16;
    return v.f;
}

// input load: raw fp32 (bf16-buffer fallback kept purely as safety)
__device__ __forceinline__ float ldq(const void* p, int i, bool f32) {
    if (f32) return ((const float*)p)[i];
    return bf2f(((const unsigned short*)p)[i]);
}

__device__ __forceinline__ float rdlane(float v, int sl) {
    return __int_as_float(__builtin_amdgcn_readlane(__float_as_int(v), sl));
}

// ---------------------------------------------------------------------------
// Prep: detect buffer dtype (parallel probe), zero counter, stage w_gate,
// fold W2@Wout (+ b2@Wout + bout), pack per-hidden-unit weights.
// wpack layout (expert-major): wpack[e*1536 + j*12 + {0..8:W1col, 9:b1,
// 10..11:W2'}] — 48B records, 16B-aligned.
// ---------------------------------------------------------------------------
__global__ void prep_kernel(const void* __restrict__ num_prop,
                            const void* __restrict__ wgate,
                            const void* __restrict__ W1,
                            const void* __restrict__ b1,
                            const void* __restrict__ W2,
                            const void* __restrict__ b2,
                            const void* __restrict__ Wout,
                            const void* __restrict__ bout,
                            unsigned int* __restrict__ cnt1,
                            int* __restrict__ flag,
                            float* __restrict__ bpp,
                            float* __restrict__ wgf,
                            float* __restrict__ wpack)
{
    __shared__ unsigned int bad;
    __shared__ int sflag;
    const int t = threadIdx.x;
    if (t == 0) { bad = 0u; *cnt1 = 0u; }
    __syncthreads();
    if (t < 72) {   // parallel dtype probe
        const unsigned short* u = (const unsigned short*)num_prop;
        int e = (u[t] >> 7) & 0xFF;
        if (e < 64 || e > 191) atomicOr(&bad, 1u);
    }
    __syncthreads();
    if (t == 0) { sflag = (int)bad; *flag = (int)bad; }
    __syncthreads();
    const bool f32 = (sflag != 0);

    if (t < 18) wgf[t] = ldq(wgate, t, f32);        // w_gate [9,2] raw fp32

    if (t < 4) {  // b''[e][o] = sum_m b2[e][m]*Wout[m][o] + bout[o]
        int e = t >> 1, o = t & 1;
        float acc = ldq(bout, o, f32);
        for (int m = 0; m < 32; ++m)
            acc += ldq(b2, e * 32 + m, f32) * ldq(Wout, m * 2 + o, f32);
        bpp[t] = acc;
    }

    const int e = t >> 7;       // 256 threads -> (e, j)
    const int j = t & 127;
    float p0 = 0.f, p1 = 0.f;
    for (int m = 0; m < 32; ++m) {
        float w = ldq(W2, (e * 128 + j) * 32 + m, f32);
        p0 += w * ldq(Wout, m * 2 + 0, f32);
        p1 += w * ldq(Wout, m * 2 + 1, f32);
    }
    float* dst = wpack + e * 1536 + j * 12;
    #pragma unroll
    for (int d = 0; d < 9; ++d)
        dst[d] = ldq(W1, (e * 9 + d) * 128 + j, f32);
    dst[9]  = ldq(b1, e * 128 + j, f32);
    dst[10] = p0;
    dst[11] = p1;
}

// one token's j-body given 12 uniform weights W[0..11] (bit-exact chain)
#define JBODY(W)                                                          \
    {                                                                     \
        float h0 = W[9], h1 = W[9], h2 = W[9], h3 = W[9];                 \
        _Pragma("unroll")                                                 \
        for (int d = 0; d < 9; ++d) {                                     \
            h0 = fmaf(x0[d], W[d], h0);                                   \
            h1 = fmaf(x1[d], W[d], h1);                                   \
            h2 = fmaf(x2[d], W[d], h2);                                   \
            h3 = fmaf(x3[d], W[d], h3);                                   \
        }                                                                 \
        h0 = fmaxf(h0, 0.f); h1 = fmaxf(h1, 0.f);                         \
        h2 = fmaxf(h2, 0.f); h3 = fmaxf(h3, 0.f);                         \
        a00 = fmaf(h0, W[10], a00); a01 = fmaf(h0, W[11], a01);           \
        a10 = fmaf(h1, W[10], a10); a11 = fmaf(h1, W[11], a11);           \
        a20 = fmaf(h2, W[10], a20); a21 = fmaf(h2, W[11], a21);           \
        a30 = fmaf(h3, W[10], a30); a31 = fmaf(h3, W[11], a31);           \
    }

// boundary-path token body: weights in this thread's float4 regs A,B,C
#define JBODYT(xk, A, B, C, ak0, ak1)                                     \
    {                                                                     \
        float h = C.y;                                                    \
        h = fmaf(xk[0], A.x, h); h = fmaf(xk[1], A.y, h);                 \
        h = fmaf(xk[2], A.z, h); h = fmaf(xk[3], A.w, h);                 \
        h = fmaf(xk[4], B.x, h); h = fmaf(xk[5], B.y, h);                 \
        h = fmaf(xk[6], B.z, h); h = fmaf(xk[7], B.w, h);                 \
        h = fmaf(xk[8], C.x, h);                                         \
        h = fmaxf(h, 0.f);                                                \
        ak0 = fmaf(h, C.z, ak0); ak1 = fmaf(h, C.w, ak1);                 \
    }

// ---------------------------------------------------------------------------
// Main: 1024 tokens/block, 4/thread. Stage weights (12KB) + x (36KB) in
// LDS. Gate 4 tokens, stable partition by expert (16 ballot-chunks in
// token order). Thread handles slots 4*tid..4*tid+3.
// Expert-uniform waves: lane l preloads records 2l,2l+1 of its expert into
// 24 VGPRs; per j-pair 24 v_readlane broadcast the records -> 4 token
// chains each. Boundary wave: per-token float4 LDS reads (per-lane addr;
// straddling thread's tokens each get their own expert's weights).
// Results bounce through LDS to token order -> coalesced float2 stores.
// ---------------------------------------------------------------------------
__global__ __launch_bounds__(TPB, 2)
void moe_main(const void* __restrict__ xg,
              const int* __restrict__ flag,
              const float* __restrict__ wgf,
              const float* __restrict__ bpp,
              const float* __restrict__ wpack,
              unsigned int* __restrict__ cnt1,
              float2* __restrict__ out)
{
    __shared__ __align__(16) float xs[TOKB * 9];   // 36864 B
    __shared__ __align__(16) float wsm[3072];      // 12288 B (both experts)
    __shared__ unsigned short smap[TOKB];          // 2048 B
    __shared__ unsigned int wcnt[16];

    const int tid  = threadIdx.x;
    const int lane = tid & 63;
    const int wave = tid >> 6;

    const bool f32 = (*flag) != 0;

    // stage weights: 12 coalesced floats per thread
    #pragma unroll
    for (int i = 0; i < 12; ++i)
        wsm[tid + i * TPB] = wpack[tid + i * TPB];

    if (f32) {   // stage x as float4 (9 per thread, coalesced 16B/lane)
        const float4* xf4 = (const float4*)xg;
        float4* xsv = (float4*)xs;
        const int g4 = blockIdx.x * (TOKB * 9 / 4);
        #pragma unroll
        for (int i = 0; i < 9; ++i)
            xsv[tid + i * TPB] = xf4[g4 + tid + i * TPB];
    } else {
        const unsigned short* xu = (const unsigned short*)xg;
        const int gbase = blockIdx.x * (TOKB * 9);
        for (int i = tid; i < TOKB * 9; i += TPB)
            xs[i] = bf2f(xu[gbase + i]);
    }
    __syncthreads();

    // --- gate 4 tokens (tokens g*256 + tid); chains match accepted kernel ---
    bool e1g[4];
    unsigned long long balg[4];
    #pragma unroll
    for (int g = 0; g < 4; ++g) {
        float l0 = 0.f, l1 = 0.f;
        #pragma unroll
        for (int d = 0; d < 9; ++d) {
            float xv = xs[(g * 256 + tid) * 9 + d];
            l0 = fmaf(xv, wgf[d * 2 + 0], l0);
            l1 = fmaf(xv, wgf[d * 2 + 1], l1);
        }
        e1g[g] = l1 > l0;          // tie -> expert 0 (stable top_k)
        balg[g] = __ballot(e1g[g]);
        if (lane == 0) wcnt[g * 4 + wave] = (unsigned int)__popcll(balg[g]);
    }
    __syncthreads();

    // --- stable partition over 1024 tokens (chunk c = g*4+wave = token order) ---
    int pres[16]; int run = 0;
    #pragma unroll
    for (int c = 0; c < 16; ++c) { pres[c] = run; run += (int)wcnt[c]; }
    const int n1 = run;
    const int n0 = TOKB - n1;
    const unsigned long long below = (1ull << lane) - 1ull;
    #pragma unroll
    for (int g = 0; g < 4; ++g) {
        const int tok = g * 256 + tid;
        const int pr  = pres[g * 4 + wave] + (int)__popcll(balg[g] & below);
        const int slot = e1g[g] ? (n0 + pr) : (tok - pr);
        smap[slot] = (unsigned short)tok;
    }
    if (tid == 0) atomicAdd(cnt1, (unsigned int)n1);
    __syncthreads();

    // --- this thread processes slots 4*tid .. 4*tid+3 ---
    const int s0 = tid * 4;
    const int tk0 = (int)smap[s0 + 0], tk1 = (int)smap[s0 + 1];
    const int tk2 = (int)smap[s0 + 2], tk3 = (int)smap[s0 + 3];
    float x0[9], x1[9], x2[9], x3[9];
    #pragma unroll
    for (int d = 0; d < 9; ++d) {
        x0[d] = xs[tk0 * 9 + d];
        x1[d] = xs[tk1 * 9 + d];
        x2[d] = xs[tk2 * 9 + d];
        x3[d] = xs[tk3 * 9 + d];
    }

    // wave's slot range = [wave*256, wave*256+256); scalarized uniformity test
    const int wslot = __builtin_amdgcn_readfirstlane(wave) << 8;
    const int n0u   = __builtin_amdgcn_readfirstlane(n0);

    float a00, a01, a10, a11, a20, a21, a30, a31;
    if (n0u <= wslot || n0u >= wslot + 256) {
        // ---- expert-uniform wave: weights in registers + v_readlane ----
        const int ew = (n0u <= wslot) ? 1 : 0;
        // lane l holds records 2l, 2l+1 of expert ew (24 VGPRs)
        float tbl[24];
        {
            const float4* src = (const float4*)(wsm + ew * 1536 + lane * 24);
            #pragma unroll
            for (int q = 0; q < 6; ++q) {
                const float4 v = src[q];
                tbl[q * 4 + 0] = v.x; tbl[q * 4 + 1] = v.y;
                tbl[q * 4 + 2] = v.z; tbl[q * 4 + 3] = v.w;
            }
        }
        const float b0 = bpp[ew * 2 + 0], b1v = bpp[ew * 2 + 1];
        a00 = b0; a01 = b1v; a10 = b0; a11 = b1v;
        a20 = b0; a21 = b1v; a30 = b0; a31 = b1v;
        #pragma unroll 2
        for (int jp = 0; jp < 64; ++jp) {   // j = 2*jp, 2*jp+1 from lane jp
            float w0[12], w1[12];
            #pragma unroll
            for (int k = 0; k < 12; ++k) {
                w0[k] = rdlane(tbl[k],      jp);
                w1[k] = rdlane(tbl[12 + k], jp);
            }
            JBODY(w0)   // j = 2*jp
            JBODY(w1)   // j = 2*jp+1
        }
    } else {
        // ---- boundary wave: per-token per-lane LDS reads (handles the
        //      straddling thread: each token uses its own expert's base) ----
        const int ex0 = ((s0 + 0) >= n0u) ? 1 : 0;
        const int ex1 = ((s0 + 1) >= n0u) ? 1 : 0;
        const int ex2 = ((s0 + 2) >= n0u) ? 1 : 0;
        const int ex3 = ((s0 + 3) >= n0u) ? 1 : 0;
        const int eb0 = ex0 * 1536, eb1 = ex1 * 1536;
        const int eb2 = ex2 * 1536, eb3 = ex3 * 1536;
        a00 = bpp[ex0 * 2 + 0]; a01 = bpp[ex0 * 2 + 1];   // FIXED (was (eb>>10)|o)
        a10 = bpp[ex1 * 2 + 0]; a11 = bpp[ex1 * 2 + 1];
        a20 = bpp[ex2 * 2 + 0]; a21 = bpp[ex2 * 2 + 1];
        a30 = bpp[ex3 * 2 + 0]; a31 = bpp[ex3 * 2 + 1];
        #pragma unroll 2
        for (int j = 0; j < 128; ++j) {
            const float4* q0 = (const float4*)(wsm + eb0 + j * 12);
            const float4* q1 = (const float4*)(wsm + eb1 + j * 12);
            const float4* q2 = (const float4*)(wsm + eb2 + j * 12);
            const float4* q3 = (const float4*)(wsm + eb3 + j * 12);
            const float4 A0 = q0[0], B0 = q0[1], C0 = q0[2];
            const float4 A1 = q1[0], B1 = q1[1], C1 = q1[2];
            const float4 A2 = q2[0], B2 = q2[1], C2 = q2[2];
            const float4 A3 = q3[0], B3 = q3[1], C3 = q3[2];
            JBODYT(x0, A0, B0, C0, a00, a01)
            JBODYT(x1, A1, B1, C1, a10, a11)
            JBODYT(x2, A2, B2, C2, a20, a21)
            JBODYT(x3, A3, B3, C3, a30, a31)
        }
    }

    // --- bounce through LDS to token order; coalesced float2 stores ---
    __syncthreads();                        // all xs/wsm reads complete
    float2* ob = (float2*)xs;               // 1024 float2 = 8192 B < xs
    ob[tk0] = make_float2(a00, a01);
    ob[tk1] = make_float2(a10, a11);
    ob[tk2] = make_float2(a20, a21);
    ob[tk3] = make_float2(a30, a31);
    __syncthreads();
    const int obase = blockIdx.x * TOKB;
    #pragma unroll
    for (int g = 0; g < 4; ++g)
        out[obase + g * 256 + tid] = ob[g * 256 + tid];
}

// Loss: gates one-hot value-1.0 -> importance == load == counts.
// cv^2 ddof=1: var=(c0-c1)^2/2, mean=N/2; loss = 0.01*2*cv^2 (~1e-9).
__global__ void finalize_kernel(const unsigned int* __restrict__ cnt1,
                                float* __restrict__ loss_out)
{
    double c1 = (double)(*cnt1);
    double c0 = (double)NTOK - c1;
    double diff = c0 - c1;
    double mean = (double)NTOK * 0.5;
    double var  = 0.5 * diff * diff;
    double cv2  = var / (mean * mean + 1e-10);
    *loss_out = (float)(0.02 * cv2);
}

extern "C" void kernel_launch(void* const* d_in, const int* in_sizes, int n_in,
                              void* d_out, int out_size, void* d_ws, size_t ws_size,
                              hipStream_t stream) {
    const void* num_prop = d_in[0]; // [N,9] fp32
    // d_in[1] = cat_prop (unused)
    const void* w_gate   = d_in[2]; // [9,2]
    const void* W1       = d_in[3]; // [2,9,128]
    const void* b1       = d_in[4]; // [2,128]
    const void* W2       = d_in[5]; // [2,128,32]
    const void* b2       = d_in[6]; // [2,32]
    const void* Wout     = d_in[7]; // [32,2]
    const void* bout     = d_in[8]; // [2]
    // d_in[9] = k (==1)

    char* ws = (char*)d_ws;
    unsigned int* cnt1 = (unsigned int*)ws;          // @0
    int* flag          = (int*)(ws + 8);             // @8
    float* bpp         = (float*)(ws + 16);          // 4 f
    float* wgf         = (float*)(ws + 64);          // 18 f
    float* wpack       = (float*)(ws + 192);         // 3072 f (expert-major)

    float*  outf = (float*)d_out;                    // FP32: N*2 + loss
    float2* out2 = (float2*)d_out;

    hipLaunchKernelGGL(prep_kernel, dim3(1), dim3(256), 0, stream,
                       num_prop, w_gate, W1, b1, W2, b2, Wout, bout,
                       cnt1, flag, bpp, wgf, wpack);
    hipLaunchKernelGGL(moe_main, dim3(NBLK), dim3(TPB), 0, stream,
                       num_prop, flag, wgf, bpp, wpack, cnt1, out2);
    hipLaunchKernelGGL(finalize_kernel, dim3(1), dim3(1), 0, stream,
                       cnt1, outf + (size_t)NTOK * 2);
}